// Round 12
// baseline (204.074 us; speedup 1.0000x reference)
//
#include <hip/hip_runtime.h>
#include <hip/hip_bf16.h>
#include <stdint.h>

// Attention: b=4, n=4097, d=128, h=8, dh=16, scale = d**-0.5.
// Interface (R5): fp32 in, fp32 out, ws >= 33.6MB usable.
// R12: qkv_proj epilogue rebuilt -- results staged in LDS, stored as 16B
// dwordx4 (128B contiguous runs per head). Hypothesis: the f16 2B-scalar
// store path has been a hidden ~75-90us dispatch since R6 (residual jumped
// 13.5 -> 117us exactly when it appeared; R9's "spill" kernel shared it and
// showed VALUBusy 9.7% = store-bound signature). attn/vt/out_proj frozen.

#define BB 4
#define NN 4097
#define NNP 4112
#define DD 128
#define HH 8
#define DH 16
#define BH (BB*HH)    // 32
#define ROWS (BB*NN)  // 16388

typedef _Float16 h4 __attribute__((ext_vector_type(4)));
typedef _Float16 h8 __attribute__((ext_vector_type(8)));
typedef __fp16   fp16v2 __attribute__((ext_vector_type(2)));
typedef float    f4 __attribute__((ext_vector_type(4)));

#if __has_builtin(__builtin_amdgcn_exp2f)
#define EXP2F(x) __builtin_amdgcn_exp2f(x)
#else
#define EXP2F(x) exp2f(x)
#endif

union H4u { h4 v; fp16v2 p[2]; };

static __device__ __forceinline__ H4u pack4u(float a, float b, float c, float d) {
    H4u u;
#if __has_builtin(__builtin_amdgcn_cvt_pkrtz)
    u.p[0] = __builtin_amdgcn_cvt_pkrtz(a, b);
    u.p[1] = __builtin_amdgcn_cvt_pkrtz(c, d);
#else
    u.v[0] = (_Float16)a; u.v[1] = (_Float16)b; u.v[2] = (_Float16)c; u.v[3] = (_Float16)d;
#endif
    return u;
}

// ---------------- K1: qkv projection, 4 rows/block, wide-store epilogue --------
__global__ __launch_bounds__(384) void qkv_proj(
    const float* __restrict__ x,
    const float* __restrict__ Wqkv,
    const float* __restrict__ bqkv,
    _Float16* __restrict__ Qh,    // [BH][NNP][16], scale*log2e folded
    _Float16* __restrict__ Kh,    // [BH][NNP][16]
    _Float16* __restrict__ Vh)    // [BH][NNP][16] row-major (transposed later)
{
    __shared__ _Float16 sh[3][4][136];   // [which][row][col], padded

    const int t  = threadIdx.x;        // 0..383 (output column)
    const int r0 = blockIdx.x * 4;     // rows r0..r0+3

    const float bias = bqkv[t];
    float acc0 = bias, acc1 = bias, acc2 = bias, acc3 = bias;

    const float* x0 = x + (size_t)r0 * DD;
    #pragma unroll 4
    for (int k = 0; k < DD; ++k) {
        const float w = Wqkv[k*384 + t];   // coalesced
        acc0 += x0[k]        * w;          // wave-uniform -> s_load
        acc1 += x0[DD + k]   * w;
        acc2 += x0[2*DD + k] * w;
        acc3 += x0[3*DD + k] * w;
    }

    const int which = t >> 7, c = t & 127;
    const float QSCALE = 0.08838834764831845f * 1.4426950408889634f; // 128^-.5 * log2e
    const float mul = (which == 0) ? QSCALE : 1.0f;

    sh[which][0][c] = (_Float16)(acc0 * mul);
    sh[which][1][c] = (_Float16)(acc1 * mul);
    sh[which][2][c] = (_Float16)(acc2 * mul);
    sh[which][3][c] = (_Float16)(acc3 * mul);
    __syncthreads();

    const int bidx0 = r0 / NN;
    const int bidx3 = (r0 + 3) / NN;

    if (bidx0 == bidx3) {
        // fast path: 192 threads x 16B stores; 128B contiguous per (which,head)
        if (t < 192) {
            const int w2  = t >> 6;          // 0=Q 1=K 2=V
            const int rem = t & 63;
            const int hd  = rem >> 3;        // head 0..7
            const int ch  = rem & 7;
            const int rr  = ch >> 1;         // row 0..3
            const int hf  = ch & 1;          // half (8 f16)
            const h8 v = *(const h8*)&sh[w2][rr][hd*16 + hf*8];
            _Float16* base = (w2 == 0) ? Qh : ((w2 == 1) ? Kh : Vh);
            const int nrow = r0 - bidx0*NN + rr;
            *(h8*)(base + (((size_t)(bidx0*HH + hd))*NNP + nrow)*DH + hf*8) = v;
        }
    } else {
        // boundary blocks (3 of 4097): scalar fallback
        const int head = c >> 4, i = c & 15;
        _Float16* base = (which == 0) ? Qh : ((which == 1) ? Kh : Vh);
        #pragma unroll
        for (int r = 0; r < 4; ++r) {
            const int row  = r0 + r;
            const int bidx = row / NN;
            const int nrow = row - bidx*NN;
            base[(((size_t)(bidx*HH + head))*NNP + nrow)*DH + i] = sh[which][r][c];
        }
    }
}

// ---------------- K1b: Vh [bh][n][16] -> Vt [bh][16][NNP] (R10-proven) ---------
__global__ __launch_bounds__(256) void vt_transpose(
    const _Float16* __restrict__ Vh,
    _Float16* __restrict__ Vt)
{
    __shared__ _Float16 tile[128][DH + 2];
    const int tl  = blockIdx.x;              // 0..32
    const int bh  = blockIdx.y;              // 0..31
    const int tid = threadIdx.x;             // 0..255
    const int n0  = tl * 128;
    const int rem = (n0 + 128 <= NNP) ? 128 : (NNP - n0);

    {
        const int r  = tid >> 1;
        const int i8 = (tid & 1) * 8;
        const int rc = (r < rem) ? r : (rem - 1);
        const h8 v = *(const h8*)(Vh + ((size_t)bh*NNP + n0 + rc)*DH + i8);
        #pragma unroll
        for (int j = 0; j < 8; ++j) tile[r][i8 + j] = v[j];
    }
    __syncthreads();
    {
        const int i    = tid >> 4;      // 0..15
        const int nseg = tid & 15;      // 0..15
        if (nseg * 8 < rem) {
            h8 v;
            #pragma unroll
            for (int j = 0; j < 8; ++j) v[j] = tile[nseg*8 + j][i];
            *(h8*)(Vt + ((size_t)bh*DH + i)*NNP + n0 + nseg*8) = v;
        }
    }
}

// ---------------- K2: MFMA flash attention, 64q/wave, split x4 (R11-frozen) ----
__global__ __launch_bounds__(256, 8) void attn_mfma(
    const _Float16* __restrict__ Qh,
    const _Float16* __restrict__ Kh,
    const _Float16* __restrict__ Vt,
    _Float16* __restrict__ PACC,   // [4][ROWS][DD] per-split normalized out (f16)
    float* __restrict__ PL)        // [4][ROWS][HH] per-split row sums
{
    const int qt   = blockIdx.x;       // 0..16
    const int bh   = blockIdx.y;       // 0..31
    const int sp   = blockIdx.z;       // 0..3
    const int tid  = threadIdx.x;
    const int wave = tid >> 6;
    const int lane = tid & 63;
    const int quad = lane >> 4;
    const int l16  = lane & 15;
    const int bidx = bh >> 3, head = bh & 7;

    const int qbase = qt*256 + wave*64;

    const _Float16* Qb = Qh + (size_t)bh*NNP*DH;
    h4 qf[4];
    #pragma unroll
    for (int g = 0; g < 4; ++g) {
        const int qr = qbase + g*16 + l16;
        const int qc = (qr < NN) ? qr : (NN-1);
        qf[g] = *(const h4*)(Qb + (size_t)qc*DH + quad*4);
    }

    f4 acc[4] = {{0,0,0,0},{0,0,0,0},{0,0,0,0},{0,0,0,0}};
    float ls[4] = {0.f,0.f,0.f,0.f};

    const int t0 = sp*64;
    const int t1 = t0 + 64;

    const _Float16* kp = Kh + ((size_t)bh*NNP + (size_t)t0*16 + l16)*DH + quad*4;
    const _Float16* vp = Vt + ((size_t)bh*DH + l16)*NNP + t0*16 + quad*4;

    h4 ak = *(const h4*)kp;
    h4 av = *(const h4*)vp;
    const f4 zero = {0.f,0.f,0.f,0.f};
#if __has_builtin(__builtin_amdgcn_fdot2)
    const fp16v2 one2 = {(__fp16)1.0f, (__fp16)1.0f};
#endif

    for (int tt = t0; tt < t1; ++tt) {
        kp += 16*DH; vp += 16;
        const h4 nak = *(const h4*)kp;   // prefetch (tile <= 256 in-bounds)
        const h4 nav = *(const h4*)vp;
        #pragma unroll
        for (int g = 0; g < 4; ++g) {
            f4 d = __builtin_amdgcn_mfma_f32_16x16x16f16(ak, qf[g], zero, 0, 0, 0);
            const float p0 = EXP2F(d[0]), p1 = EXP2F(d[1]), p2 = EXP2F(d[2]), p3 = EXP2F(d[3]);
            const H4u pb = pack4u(p0, p1, p2, p3);
#if __has_builtin(__builtin_amdgcn_fdot2)
            ls[g] = __builtin_amdgcn_fdot2(pb.p[0], one2,
                     __builtin_amdgcn_fdot2(pb.p[1], one2, ls[g], false), false);
#else
            ls[g] += (p0 + p1) + (p2 + p3);
#endif
            acc[g] = __builtin_amdgcn_mfma_f32_16x16x16f16(av, pb.v, acc[g], 0, 0, 0);
        }
        ak = nak; av = nav;
    }

    if (sp == 3) {   // tile 256: keys 4096..4111; only key 4096 (quad==0, reg 0) valid
        #pragma unroll
        for (int g = 0; g < 4; ++g) {
            f4 d = __builtin_amdgcn_mfma_f32_16x16x16f16(ak, qf[g], zero, 0, 0, 0);
            const float p0 = (quad == 0) ? EXP2F(d[0]) : 0.f;
            ls[g] += p0;
            const H4u pb = pack4u(p0, 0.f, 0.f, 0.f);
            acc[g] = __builtin_amdgcn_mfma_f32_16x16x16f16(av, pb.v, acc[g], 0, 0, 0);
        }
    }

    const size_t rb = (size_t)sp*ROWS + (size_t)bidx*NN;
    #pragma unroll
    for (int g = 0; g < 4; ++g) {
        float l = ls[g];
        l += __shfl_xor(l, 16);
        l += __shfl_xor(l, 32);
        const int qr = qbase + g*16 + l16;
        if (qr < NN) {
            const float inv = 1.0f / l;   // per-split normalize: f16-safe range
            const H4u st = pack4u(acc[g][0]*inv, acc[g][1]*inv, acc[g][2]*inv, acc[g][3]*inv);
            *(h4*)(PACC + (rb + qr)*DD + head*DH + quad*4) = st.v;
            if (quad == 0) PL[(rb + qr)*HH + head] = l;
        }
    }
}

// ---------------- K3: fused merge + out = AO @ W_out + b_out (R11-frozen) ------
__global__ __launch_bounds__(128) void out_proj_fused(
    const _Float16* __restrict__ PACC,
    const float* __restrict__ PL,
    const float* __restrict__ Wout,
    const float* __restrict__ bout,
    float* __restrict__ out)
{
    __shared__ float lls[256];     // [sp][r][h]
    __shared__ float linv[64];     // [r][h]
    __shared__ float xr[8*DD];     // merged+normalized AO rows

    const int t  = threadIdx.x;    // 0..127 (output column)
    const int r0 = blockIdx.x * 8; // rows r0..r0+7

    #pragma unroll
    for (int u = 0; u < 2; ++u) {
        const int idx = t + u*128;
        const int sp = idx >> 6, r = (idx >> 3) & 7, h = idx & 7;
        const int row = (r0 + r < ROWS) ? (r0 + r) : (ROWS - 1);
        lls[idx] = PL[((size_t)sp*ROWS + row)*HH + h];
    }
    __syncthreads();
    if (t < 64) {
        const float s = lls[t] + lls[64 + t] + lls[128 + t] + lls[192 + t];
        linv[t] = 1.0f / s;
    }
    __syncthreads();

    const int head = t >> 4;
    #pragma unroll
    for (int r = 0; r < 8; ++r) {
        const int row = (r0 + r < ROWS) ? (r0 + r) : (ROWS - 1);
        float num = 0.f;
        #pragma unroll
        for (int sp = 0; sp < 4; ++sp)
            num += lls[sp*64 + r*8 + head]
                 * (float)PACC[((size_t)sp*ROWS + row)*DD + t];
        xr[r*DD + t] = num * linv[r*8 + head];
    }
    __syncthreads();

    const float bias = bout[t];
    float acc[8];
    #pragma unroll
    for (int r = 0; r < 8; ++r) acc[r] = bias;

    #pragma unroll 4
    for (int k = 0; k < DD; ++k) {
        const float w = Wout[k*DD + t];
        #pragma unroll
        for (int r = 0; r < 8; ++r)
            acc[r] += xr[r*DD + k] * w;
    }

    #pragma unroll
    for (int r = 0; r < 8; ++r) {
        const int row = r0 + r;
        if (row < ROWS) out[(size_t)row*DD + t] = acc[r];
    }
}

extern "C" void kernel_launch(void* const* d_in, const int* in_sizes, int n_in,
                              void* d_out, int out_size, void* d_ws, size_t ws_size,
                              hipStream_t stream) {
    const float* x    = (const float*)d_in[0];
    const float* Wqkv = (const float*)d_in[1];
    const float* bqkv = (const float*)d_in[2];
    const float* Wout = (const float*)d_in[3];
    const float* bout = (const float*)d_in[4];
    for (int i = 0; i < n_in; ++i) {
        switch (in_sizes[i]) {
            case 2097664: x    = (const float*)d_in[i]; break;
            case 49152:   Wqkv = (const float*)d_in[i]; break;
            case 384:     bqkv = (const float*)d_in[i]; break;
            case 16384:   Wout = (const float*)d_in[i]; break;
            case 128:     bout = (const float*)d_in[i]; break;
            default: break;
        }
    }
    float* out = (float*)d_out;

    const size_t perh = (size_t)BH * NNP * DH;            // 2,105,344 f16
    _Float16* Qh   = (_Float16*)d_ws;                     // 4.21 MB
    _Float16* Kh   = Qh + perh;                           // 4.21 MB
    _Float16* Vt   = Kh + perh;                           // 4.21 MB
    _Float16* Vh   = Vt + perh;                           // 4.21 MB (dead after transpose)
    _Float16* PACC = Vh;                                  // [4][ROWS][DD] f16, overlays Vh
    float*    PL   = (float*)(PACC + (size_t)4*ROWS*DD);  // [4][ROWS][HH] -> total 31.5 MB

    hipLaunchKernelGGL(qkv_proj, dim3(ROWS/4), dim3(384), 0, stream,
                       x, Wqkv, bqkv, Qh, Kh, Vh);
    hipLaunchKernelGGL(vt_transpose, dim3(33, BH), dim3(256), 0, stream,
                       Vh, Vt);
    hipLaunchKernelGGL(attn_mfma, dim3(17, BH, 4), dim3(256), 0, stream,
                       Qh, Kh, Vt, PACC, PL);
    hipLaunchKernelGGL(out_proj_fused, dim3((ROWS + 7)/8), dim3(128), 0, stream,
                       PACC, PL, Wout, bout, out);
}

// Round 13
// 195.536 us; speedup vs baseline: 1.0437x; 1.0437x over previous
//
#include <hip/hip_runtime.h>
#include <hip/hip_bf16.h>
#include <stdint.h>

// Attention: b=4, n=4097, d=128, h=8, dh=16, scale = d**-0.5.
// Interface (R5): fp32 in, fp32 out, ws >= 33.6MB usable.
// R13: projections moved to MFMA. R12 proved stores are NOT the residual
// (LDS-staged wide stores = zero delta); arithmetic says the residual is
// out_proj_fused's 1024 uniform ds_read_b32/thread (~40us) + qkv's 803MB
// Wqkv L2 re-read (~25us). Both are GEMM-shaped -> v_mfma_f32_16x16x16f16
// with the R6-verified fragment layouts. attn_mfma/vt_transpose frozen.

#define BB 4
#define NN 4097
#define NNP 4112
#define DD 128
#define HH 8
#define DH 16
#define BH (BB*HH)    // 32
#define ROWS (BB*NN)  // 16388
#define MT  1025      // ceil(ROWS/16) m-tiles

typedef _Float16 h4 __attribute__((ext_vector_type(4)));
typedef _Float16 h8 __attribute__((ext_vector_type(8)));
typedef __fp16   fp16v2 __attribute__((ext_vector_type(2)));
typedef float    f4 __attribute__((ext_vector_type(4)));

#define QSCALE (0.08838834764831845f * 1.4426950408889634f)  // 128^-.5 * log2e

#if __has_builtin(__builtin_amdgcn_exp2f)
#define EXP2F(x) __builtin_amdgcn_exp2f(x)
#else
#define EXP2F(x) exp2f(x)
#endif

union H4u { h4 v; fp16v2 p[2]; };

static __device__ __forceinline__ H4u pack4u(float a, float b, float c, float d) {
    H4u u;
#if __has_builtin(__builtin_amdgcn_cvt_pkrtz)
    u.p[0] = __builtin_amdgcn_cvt_pkrtz(a, b);
    u.p[1] = __builtin_amdgcn_cvt_pkrtz(c, d);
#else
    u.v[0] = (_Float16)a; u.v[1] = (_Float16)b; u.v[2] = (_Float16)c; u.v[3] = (_Float16)d;
#endif
    return u;
}

// ---------------- K0: prep — x->f16, W_qkv^T (Q-scaled) + W_out^T in f16 -------
__global__ __launch_bounds__(256) void prep(
    const float* __restrict__ x,
    const float* __restrict__ Wqkv,
    const float* __restrict__ Wout,
    _Float16* __restrict__ x16,     // [ROWS][128]
    _Float16* __restrict__ WqkvT,   // [384][128], rows 0..127 pre-scaled by QSCALE
    _Float16* __restrict__ WoutT)   // [128][128]
{
    const int id = blockIdx.x*256 + threadIdx.x;
    const int NX8 = ROWS*DD/8;                  // 262208
    if (id < NX8) {
        const float4* s = (const float4*)(x + (size_t)id*8);
        const float4 a = s[0], b = s[1];
        const H4u u0 = pack4u(a.x, a.y, a.z, a.w);
        const H4u u1 = pack4u(b.x, b.y, b.z, b.w);
        h4* d = (h4*)(x16 + (size_t)id*8);
        d[0] = u0.v; d[1] = u1.v;
    } else if (id < NX8 + 384*128) {
        const int e = id - NX8;
        const int n = e >> 7, k = e & 127;
        const float s = (n < 128) ? QSCALE : 1.0f;
        WqkvT[e] = (_Float16)(Wqkv[k*384 + n] * s);
    } else if (id < NX8 + 384*128 + 128*128) {
        const int e = id - NX8 - 384*128;
        const int n = e >> 7, k = e & 127;
        WoutT[e] = (_Float16)(Wout[k*128 + n]);
    }
}

// ---------------- K1: qkv = x16 @ WqkvT^T + b, via MFMA ----------------
// D[m=row(quad*4+reg)][n=col(l16)]; A[m=l16][k=quad*4+j]; B[k=quad*4+j][n=l16].
__global__ __launch_bounds__(256) void qkv_mfma(
    const _Float16* __restrict__ x16,
    const _Float16* __restrict__ WqkvT,
    const float* __restrict__ bqkv,
    _Float16* __restrict__ Qh,    // [BH][NNP][16]
    _Float16* __restrict__ Kh,    // [BH][NNP][16]
    _Float16* __restrict__ Vh)    // [BH][NNP][16] row-major
{
    const int wid  = blockIdx.x*4 + (threadIdx.x >> 6);   // m-tile
    if (wid >= MT) return;
    const int lane = threadIdx.x & 63;
    const int quad = lane >> 4, l16 = lane & 15;

    const int arow = wid*16 + l16;
    const int arc  = (arow < ROWS) ? arow : (ROWS - 1);
    h4 af[8];
    #pragma unroll
    for (int kk = 0; kk < 8; ++kk)
        af[kk] = *(const h4*)(x16 + (size_t)arc*DD + kk*16 + quad*4);

    const int r0 = wid*16 + quad*4;

    for (int nt = 0; nt < 24; nt += 2) {
        const float b0 = bqkv[nt*16 + l16]      * ((nt   < 8) ? QSCALE : 1.0f);
        const float b1 = bqkv[nt*16 + 16 + l16] * ((nt+1 < 8) ? QSCALE : 1.0f);
        f4 a0 = {b0,b0,b0,b0}, a1 = {b1,b1,b1,b1};
        #pragma unroll
        for (int kk = 0; kk < 8; ++kk) {
            const h4 bf0 = *(const h4*)(WqkvT + (size_t)(nt*16     + l16)*DD + kk*16 + quad*4);
            const h4 bf1 = *(const h4*)(WqkvT + (size_t)(nt*16 + 16 + l16)*DD + kk*16 + quad*4);
            a0 = __builtin_amdgcn_mfma_f32_16x16x16f16(af[kk], bf0, a0, 0, 0, 0);
            a1 = __builtin_amdgcn_mfma_f32_16x16x16f16(af[kk], bf1, a1, 0, 0, 0);
        }
        #pragma unroll
        for (int u = 0; u < 2; ++u) {
            const int ntc = nt + u;
            const int which = ntc >> 3, head = ntc & 7;
            _Float16* base = (which == 0) ? Qh : ((which == 1) ? Kh : Vh);
            const f4 av = u ? a1 : a0;
            #pragma unroll
            for (int r = 0; r < 4; ++r) {
                const int row = r0 + r;
                if (row < ROWS) {
                    const int bidx = row / NN;
                    const int nrow = row - bidx*NN;
                    base[((size_t)(bidx*HH + head)*NNP + nrow)*DH + l16] = (_Float16)av[r];
                }
            }
        }
    }
}

// ---------------- K1b: Vh [bh][n][16] -> Vt [bh][16][NNP] (R10-proven) ---------
__global__ __launch_bounds__(256) void vt_transpose(
    const _Float16* __restrict__ Vh,
    _Float16* __restrict__ Vt)
{
    __shared__ _Float16 tile[128][DH + 2];
    const int tl  = blockIdx.x;              // 0..32
    const int bh  = blockIdx.y;              // 0..31
    const int tid = threadIdx.x;             // 0..255
    const int n0  = tl * 128;
    const int rem = (n0 + 128 <= NNP) ? 128 : (NNP - n0);

    {
        const int r  = tid >> 1;
        const int i8 = (tid & 1) * 8;
        const int rc = (r < rem) ? r : (rem - 1);
        const h8 v = *(const h8*)(Vh + ((size_t)bh*NNP + n0 + rc)*DH + i8);
        #pragma unroll
        for (int j = 0; j < 8; ++j) tile[r][i8 + j] = v[j];
    }
    __syncthreads();
    {
        const int i    = tid >> 4;      // 0..15
        const int nseg = tid & 15;      // 0..15
        if (nseg * 8 < rem) {
            h8 v;
            #pragma unroll
            for (int j = 0; j < 8; ++j) v[j] = tile[nseg*8 + j][i];
            *(h8*)(Vt + ((size_t)bh*DH + i)*NNP + n0 + nseg*8) = v;
        }
    }
}

// ---------------- K2: MFMA flash attention (R11-frozen) ----------------
__global__ __launch_bounds__(256, 8) void attn_mfma(
    const _Float16* __restrict__ Qh,
    const _Float16* __restrict__ Kh,
    const _Float16* __restrict__ Vt,
    _Float16* __restrict__ PACC,   // [4][ROWS][DD] per-split normalized out (f16)
    float* __restrict__ PL)        // [4][ROWS][HH] per-split row sums
{
    const int qt   = blockIdx.x;       // 0..16
    const int bh   = blockIdx.y;       // 0..31
    const int sp   = blockIdx.z;       // 0..3
    const int tid  = threadIdx.x;
    const int wave = tid >> 6;
    const int lane = tid & 63;
    const int quad = lane >> 4;
    const int l16  = lane & 15;
    const int bidx = bh >> 3, head = bh & 7;

    const int qbase = qt*256 + wave*64;

    const _Float16* Qb = Qh + (size_t)bh*NNP*DH;
    h4 qf[4];
    #pragma unroll
    for (int g = 0; g < 4; ++g) {
        const int qr = qbase + g*16 + l16;
        const int qc = (qr < NN) ? qr : (NN-1);
        qf[g] = *(const h4*)(Qb + (size_t)qc*DH + quad*4);
    }

    f4 acc[4] = {{0,0,0,0},{0,0,0,0},{0,0,0,0},{0,0,0,0}};
    float ls[4] = {0.f,0.f,0.f,0.f};

    const int t0 = sp*64;
    const int t1 = t0 + 64;

    const _Float16* kp = Kh + ((size_t)bh*NNP + (size_t)t0*16 + l16)*DH + quad*4;
    const _Float16* vp = Vt + ((size_t)bh*DH + l16)*NNP + t0*16 + quad*4;

    h4 ak = *(const h4*)kp;
    h4 av = *(const h4*)vp;
    const f4 zero = {0.f,0.f,0.f,0.f};
#if __has_builtin(__builtin_amdgcn_fdot2)
    const fp16v2 one2 = {(__fp16)1.0f, (__fp16)1.0f};
#endif

    for (int tt = t0; tt < t1; ++tt) {
        kp += 16*DH; vp += 16;
        const h4 nak = *(const h4*)kp;   // prefetch (tile <= 256 in-bounds)
        const h4 nav = *(const h4*)vp;
        #pragma unroll
        for (int g = 0; g < 4; ++g) {
            f4 d = __builtin_amdgcn_mfma_f32_16x16x16f16(ak, qf[g], zero, 0, 0, 0);
            const float p0 = EXP2F(d[0]), p1 = EXP2F(d[1]), p2 = EXP2F(d[2]), p3 = EXP2F(d[3]);
            const H4u pb = pack4u(p0, p1, p2, p3);
#if __has_builtin(__builtin_amdgcn_fdot2)
            ls[g] = __builtin_amdgcn_fdot2(pb.p[0], one2,
                     __builtin_amdgcn_fdot2(pb.p[1], one2, ls[g], false), false);
#else
            ls[g] += (p0 + p1) + (p2 + p3);
#endif
            acc[g] = __builtin_amdgcn_mfma_f32_16x16x16f16(av, pb.v, acc[g], 0, 0, 0);
        }
        ak = nak; av = nav;
    }

    if (sp == 3) {   // tile 256: keys 4096..4111; only key 4096 (quad==0, reg 0) valid
        #pragma unroll
        for (int g = 0; g < 4; ++g) {
            f4 d = __builtin_amdgcn_mfma_f32_16x16x16f16(ak, qf[g], zero, 0, 0, 0);
            const float p0 = (quad == 0) ? EXP2F(d[0]) : 0.f;
            ls[g] += p0;
            const H4u pb = pack4u(p0, 0.f, 0.f, 0.f);
            acc[g] = __builtin_amdgcn_mfma_f32_16x16x16f16(av, pb.v, acc[g], 0, 0, 0);
        }
    }

    const size_t rb = (size_t)sp*ROWS + (size_t)bidx*NN;
    #pragma unroll
    for (int g = 0; g < 4; ++g) {
        float l = ls[g];
        l += __shfl_xor(l, 16);
        l += __shfl_xor(l, 32);
        const int qr = qbase + g*16 + l16;
        if (qr < NN) {
            const float inv = 1.0f / l;   // per-split normalize: f16-safe range
            const H4u st = pack4u(acc[g][0]*inv, acc[g][1]*inv, acc[g][2]*inv, acc[g][3]*inv);
            *(h4*)(PACC + (rb + qr)*DD + head*DH + quad*4) = st.v;
            if (quad == 0) PL[(rb + qr)*HH + head] = l;
        }
    }
}

// ---------------- K3: merged-AO @ Wout + b via MFMA ----------------
// A-frag built from 4-split merge (head == kk for each k-tile: exact softmax).
__global__ __launch_bounds__(256) void out_mfma(
    const _Float16* __restrict__ PACC,
    const float* __restrict__ PL,
    const _Float16* __restrict__ WoutT,   // [128][128]
    const float* __restrict__ bout,
    float* __restrict__ out)
{
    const int wid  = blockIdx.x*4 + (threadIdx.x >> 6);   // m-tile
    if (wid >= MT) return;
    const int lane = threadIdx.x & 63;
    const int quad = lane >> 4, l16 = lane & 15;

    const int arow = wid*16 + l16;
    const int arc  = (arow < ROWS) ? arow : (ROWS - 1);

    h4 af[8];
    #pragma unroll
    for (int kk = 0; kk < 8; ++kk) {
        float n0 = 0.f, n1 = 0.f, n2 = 0.f, n3 = 0.f, lsum = 0.f;
        #pragma unroll
        for (int sp = 0; sp < 4; ++sp) {
            const float l = PL[((size_t)sp*ROWS + arc)*HH + kk];   // head == kk
            lsum += l;
            const h4 p = *(const h4*)(PACC + ((size_t)sp*ROWS + arc)*DD + kk*16 + quad*4);
            n0 += l*(float)p[0]; n1 += l*(float)p[1];
            n2 += l*(float)p[2]; n3 += l*(float)p[3];
        }
        const float inv = 1.0f / lsum;
        const H4u u = pack4u(n0*inv, n1*inv, n2*inv, n3*inv);
        af[kk] = u.v;
    }

    const int r0 = wid*16 + quad*4;

    for (int nt = 0; nt < 8; nt += 2) {
        const float b0 = bout[nt*16 + l16];
        const float b1 = bout[nt*16 + 16 + l16];
        f4 a0 = {b0,b0,b0,b0}, a1 = {b1,b1,b1,b1};
        #pragma unroll
        for (int kk = 0; kk < 8; ++kk) {
            const h4 bf0 = *(const h4*)(WoutT + (size_t)(nt*16      + l16)*DD + kk*16 + quad*4);
            const h4 bf1 = *(const h4*)(WoutT + (size_t)(nt*16 + 16 + l16)*DD + kk*16 + quad*4);
            a0 = __builtin_amdgcn_mfma_f32_16x16x16f16(af[kk], bf0, a0, 0, 0, 0);
            a1 = __builtin_amdgcn_mfma_f32_16x16x16f16(af[kk], bf1, a1, 0, 0, 0);
        }
        #pragma unroll
        for (int r = 0; r < 4; ++r) {
            const int row = r0 + r;
            if (row < ROWS) {
                out[(size_t)row*DD + nt*16      + l16] = a0[r];
                out[(size_t)row*DD + nt*16 + 16 + l16] = a1[r];
            }
        }
    }
}

extern "C" void kernel_launch(void* const* d_in, const int* in_sizes, int n_in,
                              void* d_out, int out_size, void* d_ws, size_t ws_size,
                              hipStream_t stream) {
    const float* x    = (const float*)d_in[0];
    const float* Wqkv = (const float*)d_in[1];
    const float* bqkv = (const float*)d_in[2];
    const float* Wout = (const float*)d_in[3];
    const float* bout = (const float*)d_in[4];
    for (int i = 0; i < n_in; ++i) {
        switch (in_sizes[i]) {
            case 2097664: x    = (const float*)d_in[i]; break;
            case 49152:   Wqkv = (const float*)d_in[i]; break;
            case 384:     bqkv = (const float*)d_in[i]; break;
            case 16384:   Wout = (const float*)d_in[i]; break;
            case 128:     bout = (const float*)d_in[i]; break;
            default: break;
        }
    }
    float* out = (float*)d_out;

    const size_t perh = (size_t)BH * NNP * DH;            // 2,105,344 f16
    _Float16* Qh   = (_Float16*)d_ws;                     // 4.21 MB
    _Float16* Kh   = Qh + perh;                           // 4.21 MB
    _Float16* Vt   = Kh + perh;                           // 4.21 MB
    _Float16* Vh   = Vt + perh;                           // 4.21 MB (dead after vt)
    _Float16* PACC = Vh;                                  // [4][ROWS][DD] f16 16.78 MB
    _Float16* x16  = Vh + perh;                           // 4.2 MB, inside PACC tail
                                                          // (dead before attn writes PACC)
    float*    PL    = (float*)(PACC + (size_t)4*ROWS*DD); // 2.1 MB
    _Float16* WqkvT = (_Float16*)(PL + (size_t)4*ROWS*HH);// 96 KB
    _Float16* WoutT = WqkvT + 384*128;                    // 32 KB -> total ~31.7 MB

    const int NX8 = ROWS*DD/8;
    const int prep_total = NX8 + 384*128 + 128*128;

    hipLaunchKernelGGL(prep, dim3((prep_total + 255)/256), dim3(256), 0, stream,
                       x, Wqkv, Wout, x16, WqkvT, WoutT);
    hipLaunchKernelGGL(qkv_mfma, dim3((MT + 3)/4), dim3(256), 0, stream,
                       x16, WqkvT, bqkv, Qh, Kh, Vh);
    hipLaunchKernelGGL(vt_transpose, dim3(33, BH), dim3(256), 0, stream,
                       Vh, Vt);
    hipLaunchKernelGGL(attn_mfma, dim3(17, BH, 4), dim3(256), 0, stream,
                       Qh, Kh, Vt, PACC, PL);
    hipLaunchKernelGGL(out_mfma, dim3((MT + 3)/4), dim3(256), 0, stream,
                       PACC, PL, WoutT, bout, out);
}